// Round 18
// baseline (356.629 us; speedup 1.0000x reference)
//
#include <hip/hip_runtime.h>
#include <hip/hip_bf16.h>

#define LEAK 0.2f

__device__ __forceinline__ float lrelu(float a) { return a > 0.0f ? a : LEAK * a; }

typedef __attribute__((ext_vector_type(8))) short short8;
typedef __attribute__((ext_vector_type(4))) float f32x4;

// bf16 RNE rounding done manually (no dependence on __hip_bfloat16 ABI).
__device__ __forceinline__ unsigned short bf16_hi_bits(float x) {
    unsigned u = __builtin_bit_cast(unsigned, x);
    unsigned r = u + 0x7fffu + ((u >> 16) & 1u);
    return (unsigned short)(r >> 16);
}
__device__ __forceinline__ float bf16_to_f32(unsigned short h) {
    unsigned u = ((unsigned)h) << 16;
    return __builtin_bit_cast(float, u);
}
__device__ __forceinline__ unsigned pack_bf16pair(float x) {
    unsigned short h = bf16_hi_bits(x);
    float lo = x - bf16_to_f32(h);
    return (unsigned)h | ((unsigned)bf16_hi_bits(lo) << 16);
}

// v_perm_b32 pair-packers: dwords are packed {hi-bf16 in low16, lo-bf16 in high16}.
__device__ __forceinline__ unsigned pack_lo16(unsigned o, unsigned e) {
    return __builtin_amdgcn_perm(o, e, 0x05040100u);
}
__device__ __forceinline__ unsigned pack_hi16(unsigned o, unsigned e) {
    return __builtin_amdgcn_perm(o, e, 0x07060302u);
}

// ---------------------------------------------------------------------------
// Fused setup (R17-verified): all independent front-end work in ONE launch.
// ---------------------------------------------------------------------------
__global__ __launch_bounds__(256) void setup_k(
    const float* __restrict__ w1, unsigned* __restrict__ wT1p,
    const float* __restrict__ w2, unsigned* __restrict__ wT2p,
    const float* __restrict__ w3, unsigned* __restrict__ wT3p,
    const float* __restrict__ x,  unsigned* __restrict__ xp,
    unsigned* __restrict__ c1p, unsigned* __restrict__ c2p,
    const float* __restrict__ fcw, unsigned* __restrict__ wfcp)
{
    const int blk = blockIdx.x;
    const int tid = threadIdx.x;

    if (blk < 12) {                       // wtr1: 96x32
        int i = blk * 256 + tid;
        if (i < 96 * 32) {
            int k = i / 32, co = i % 32;
            float v = (k < 75) ? w1[(size_t)co * 75 + k] : 0.0f;
            wT1p[i] = pack_bf16pair(v);
        }
    } else if (blk < 212) {               // wtr2: 800x64
        int i = (blk - 12) * 256 + tid;
        if (i < 800 * 64) {
            int k = i / 64, co = i % 64;
            wT2p[i] = pack_bf16pair(w2[(size_t)co * 800 + k]);
        }
    } else if (blk < 500) {               // wtr3: 576x128
        int i = (blk - 212) * 256 + tid;
        if (i < 576 * 128) {
            int k = i / 128, co = i % 128;
            wT3p[i] = pack_bf16pair(w3[(size_t)co * 576 + k]);
        }
    } else if (blk < 5972) {              // pad_x: 32*3*57 blocks
        int b2 = blk - 500;
        int r4 = b2 % 57, ic = b2 / 57;
        int wid = tid >> 6, lane = tid & 63;
        int row = r4 * 4 + wid;
        const float* __restrict__ src = x + (size_t)ic * 224 * 224 + (size_t)(row - 2) * 224;
        unsigned* __restrict__ dst = xp + (size_t)ic * 228 * 228 + (size_t)row * 228;
        bool rok = (row >= 2) && (row < 226);
        for (int c = lane; c < 228; c += 64) {
            float v = 0.0f;
            if (rok && c >= 2 && c < 226) v = src[c - 2];
            dst[c] = pack_bf16pair(v);
        }
    } else if (blk < 6996) {              // zb c1p: 1024 planes
        unsigned* base = c1p + (size_t)(blk - 5972) * (116 * 120);
        for (int t = tid; t < 928; t += 256) {
            int idx;
            if (t < 480) {
                int r = t / 120, c = t - r * 120;
                int row = (r < 2) ? r : r + 112;
                idx = row * 120 + c;
            } else {
                int s = t - 480;
                int r = s >> 2, c = s & 3;
                int col = (c < 2) ? (c + 2) : (c + 114);
                idx = (r + 2) * 120 + col;
            }
            base[idx] = 0u;
        }
    } else if (blk < 7508) {              // zb c2p: 2048 planes, 4 per block
        int plane = (blk - 6996) * 4 + (tid >> 6);
        int lane  = tid & 63;
        unsigned* base = c2p + (size_t)plane * (58 * 64);
        for (int t = lane; t < 240; t += 64) {
            int idx;
            if (t < 128) {
                int r = t >> 6, c = t & 63;
                idx = (r ? 57 : 0) * 64 + c;
            } else {
                int s = t - 128;
                int r = (s >> 1) + 1;
                idx = r * 64 + ((s & 1) ? 60 : 3);
            }
            base[idx] = 0u;
        }
    } else {                              // split_pack fcw: 3,276,800 elems
        for (int i = (blk - 7508) * 256 + tid; i < 3276800; i += 4096 * 256)
            wfcp[i] = pack_bf16pair(fcw[i]);
    }
}

// ---------------------------------------------------------------------------
// conv1 as bf16 hi/lo split-GEMM on MFMA (R11-verified). CO=32, KP=96, ST=2.
// ---------------------------------------------------------------------------
__global__ __launch_bounds__(256, 4) void conv1_mfma_k(
    const unsigned* __restrict__ src,   // packed xpad [img*3+ci][228][228]
    const unsigned* __restrict__ wp,    // packed wT1 [96][32]
    const float* __restrict__ bias,
    unsigned* __restrict__ outp)        // packed c1p [img*32+co][116][120]
{
    // dwords: AH 0(640) | AL 640 | BH 1280(2560) | BL 3840 ; total 6400 dw
    __shared__ unsigned ldsu[6400];
    __shared__ int offtab[96];
    short* const lds = (short*)ldsu;

    const int tid  = threadIdx.x;
    const int lane = tid & 63;
    const int wv   = tid >> 6;
    const int bx   = blockIdx.x;        // 98 px tiles
    const int bz   = blockIdx.y;        // 32 imgs

    if (tid < 96) {
        int k = min(tid, 74);           // clamp padded-K tail
        int ci = k / 25, r = k - ci * 25;
        int kh = r / 5, kw = r - kh * 5;
        offtab[tid] = (ci * 228 + kh) * 228 + kw;
    }
    __syncthreads();

    const int brow = tid & 127, half = tid >> 7;
    const int bn   = bx * 128 + brow;
    const int boh  = bn / 112, bow = bn % 112;
    const unsigned* __restrict__ bsrc =
        src + ((size_t)(bz * 3) * 228 + boh * 2) * 228 + bow * 2;
    const int arow = tid & 31, ks = (tid >> 5) & 3;

    unsigned Bu[16], Au[8];
    auto gather = [&](int it) {
        const int k0 = it * 32;
#pragma unroll
        for (int c = 0; c < 2; ++c) {
            int kb = k0 + (half * 2 + c) * 8;
            int4 o0 = *(const int4*)&offtab[kb];
            int4 o1 = *(const int4*)&offtab[kb + 4];
            Bu[c * 8 + 0] = bsrc[o0.x]; Bu[c * 8 + 1] = bsrc[o0.y];
            Bu[c * 8 + 2] = bsrc[o0.z]; Bu[c * 8 + 3] = bsrc[o0.w];
            Bu[c * 8 + 4] = bsrc[o1.x]; Bu[c * 8 + 5] = bsrc[o1.y];
            Bu[c * 8 + 6] = bsrc[o1.z]; Bu[c * 8 + 7] = bsrc[o1.w];
        }
        if (tid < 128) {
            const unsigned* __restrict__ wk = wp + (size_t)(k0 + ks * 8) * 32 + arow;
#pragma unroll
            for (int j = 0; j < 8; ++j) Au[j] = wk[j * 32];
        }
    };

    f32x4 acc[2][2] = {};
    const int r15 = lane & 15, kg = lane >> 4;

    gather(0);
    for (int it = 0; it < 3; ++it) {
        {
            uint4 vh, vl;
#pragma unroll
            for (int c = 0; c < 2; ++c) {
                vh.x = pack_lo16(Bu[c*8+1], Bu[c*8+0]); vl.x = pack_hi16(Bu[c*8+1], Bu[c*8+0]);
                vh.y = pack_lo16(Bu[c*8+3], Bu[c*8+2]); vl.y = pack_hi16(Bu[c*8+3], Bu[c*8+2]);
                vh.z = pack_lo16(Bu[c*8+5], Bu[c*8+4]); vl.z = pack_hi16(Bu[c*8+5], Bu[c*8+4]);
                vh.w = pack_lo16(Bu[c*8+7], Bu[c*8+6]); vl.w = pack_hi16(Bu[c*8+7], Bu[c*8+6]);
                *(uint4*)&ldsu[1280 + brow * 20 + (half * 2 + c) * 4] = vh;
                *(uint4*)&ldsu[3840 + brow * 20 + (half * 2 + c) * 4] = vl;
            }
            if (tid < 128) {
                vh.x = pack_lo16(Au[1], Au[0]); vl.x = pack_hi16(Au[1], Au[0]);
                vh.y = pack_lo16(Au[3], Au[2]); vl.y = pack_hi16(Au[3], Au[2]);
                vh.z = pack_lo16(Au[5], Au[4]); vl.z = pack_hi16(Au[5], Au[4]);
                vh.w = pack_lo16(Au[7], Au[6]); vl.w = pack_hi16(Au[7], Au[6]);
                *(uint4*)&ldsu[arow * 20 + ks * 4]       = vh;
                *(uint4*)&ldsu[640 + arow * 20 + ks * 4] = vl;
            }
        }
        __syncthreads();
        if (it + 1 < 3) gather(it + 1);

        const short* AsH = lds;
        const short* AsL = lds + 1280;
        const short* BsH = lds + 2560;
        const short* BsL = lds + 7680;
        short8 aH[2], aL[2], bH[2], bL[2];
#pragma unroll
        for (int tq = 0; tq < 2; ++tq) {
            const int ra = (tq * 16 + r15) * 40 + kg * 8;
            aH[tq] = *(const short8*)&AsH[ra];
            aL[tq] = *(const short8*)&AsL[ra];
            const int rb = (wv * 32 + tq * 16 + r15) * 40 + kg * 8;
            bH[tq] = *(const short8*)&BsH[rb];
            bL[tq] = *(const short8*)&BsL[rb];
        }
#pragma unroll
        for (int ct = 0; ct < 2; ++ct)
#pragma unroll
            for (int pt = 0; pt < 2; ++pt) {
                acc[ct][pt] = __builtin_amdgcn_mfma_f32_16x16x32_bf16(aH[ct], bH[pt], acc[ct][pt], 0, 0, 0);
                acc[ct][pt] = __builtin_amdgcn_mfma_f32_16x16x32_bf16(aH[ct], bL[pt], acc[ct][pt], 0, 0, 0);
                acc[ct][pt] = __builtin_amdgcn_mfma_f32_16x16x32_bf16(aL[ct], bH[pt], acc[ct][pt], 0, 0, 0);
            }
        __syncthreads();
    }

    // C/D: col = lane&15 -> px, row = (lane>>4)*4+reg -> co
#pragma unroll
    for (int ct = 0; ct < 2; ++ct)
#pragma unroll
        for (int pt = 0; pt < 2; ++pt)
#pragma unroll
            for (int rg = 0; rg < 4; ++rg) {
                int co = ct * 16 + kg * 4 + rg;
                int px = bx * 128 + wv * 32 + pt * 16 + r15;
                int poh = px / 112, pw_ = px % 112;
                float v = acc[ct][pt][rg] + bias[co];
                outp[((size_t)(bz * 32 + co) * 116 + poh + 2) * 120 + pw_ + 4] =
                    pack_bf16pair(lrelu(v));
            }
}

// ---------------------------------------------------------------------------
// Conv as bf16 hi/lo split-GEMM on MFMA (conv2/conv3) — v3 + co-tiling CT
// (R16-verified: conv2 CT=1 ~73us, conv3 CT=2).
// ---------------------------------------------------------------------------
template<int CI, int ST, int KH, int KW, int KP,
         int PIH, int PIW, int LP,
         int CO, int OW, int OSH, int OSW, int OR0, int OC0, bool POUT, int CT>
__global__ __launch_bounds__(256, 4) void conv_mfma_k(
    const unsigned* __restrict__ src,   // packed act [img*CI+ci][PIH][PIW]
    const unsigned* __restrict__ wp,    // packed wT  [KP][CO]
    const float* __restrict__ bias,
    void* __restrict__ outv)
{
    constexpr int KT  = KP / 32;
    constexpr int COB = CT * 64;        // co per block
    __shared__ unsigned ldsu[CT * 2560 + 2560];
    __shared__ int offtab[KP];
    short* const lds = (short*)ldsu;

    const int tid  = threadIdx.x;
    const int lane = tid & 63;
    const int wv   = tid >> 6;          // wave 0..3
    const int bx   = blockIdx.x;        // 49 px tiles
    const int by   = blockIdx.y;        // CO/COB co tiles
    const int bz   = blockIdx.z;        // 32 imgs

    for (int k = tid; k < KP; k += 256) {
        int ci = k / (KH * KW), r = k - ci * (KH * KW);
        int kh = r / KW, kw = r - kh * KW;
        offtab[k] = (ci * PIH + kh) * PIW + kw;
    }
    __syncthreads();

    const int row = lane;               // staging row; k-slot = wave (8 k each)
    const int n   = bx * 64 + row;      // 0..3135
    const int oh  = n / OW, ow = n % OW;
    const unsigned* __restrict__ bsrc =
        src + ((size_t)(bz * CI) * PIH + oh * ST) * PIW + ow * ST + LP;
    const unsigned* __restrict__ wsrc = wp + (size_t)(wv * 8) * CO + by * COB + row;

    unsigned Au[CT][8], Bu[8];
    auto gatherA = [&](int it) {
        const unsigned* __restrict__ wk = wsrc + (size_t)it * 32 * CO;
#pragma unroll
        for (int c2 = 0; c2 < CT; ++c2)
#pragma unroll
            for (int j = 0; j < 8; ++j) Au[c2][j] = wk[j * CO + c2 * 64];
    };
    auto gatherB = [&](int4 o0, int4 o1) {
        Bu[0] = bsrc[o0.x]; Bu[1] = bsrc[o0.y]; Bu[2] = bsrc[o0.z]; Bu[3] = bsrc[o0.w];
        Bu[4] = bsrc[o1.x]; Bu[5] = bsrc[o1.y]; Bu[6] = bsrc[o1.z]; Bu[7] = bsrc[o1.w];
    };

    f32x4 acc[CT][2][2] = {};

    const int cw = wv & 1, pw = wv >> 1;
    const int r15 = lane & 15, kg = lane >> 4;

    int4 o0 = *(const int4*)&offtab[wv * 8];
    int4 o1 = *(const int4*)&offtab[wv * 8 + 4];
    gatherA(0); gatherB(o0, o1);
    for (int it = 0; it < KT; ++it) {
        int4 n0, n1;
        if (it + 1 < KT) {
            const int nk = (it + 1) * 32 + wv * 8;
            n0 = *(const int4*)&offtab[nk];
            n1 = *(const int4*)&offtab[nk + 4];
        }
        {
            uint4 vh, vl;
#pragma unroll
            for (int c2 = 0; c2 < CT; ++c2) {
                const int aidx = (c2 * 64 + row) * 20 + wv * 4;
                vh.x = pack_lo16(Au[c2][1], Au[c2][0]); vl.x = pack_hi16(Au[c2][1], Au[c2][0]);
                vh.y = pack_lo16(Au[c2][3], Au[c2][2]); vl.y = pack_hi16(Au[c2][3], Au[c2][2]);
                vh.z = pack_lo16(Au[c2][5], Au[c2][4]); vl.z = pack_hi16(Au[c2][5], Au[c2][4]);
                vh.w = pack_lo16(Au[c2][7], Au[c2][6]); vl.w = pack_hi16(Au[c2][7], Au[c2][6]);
                *(uint4*)&ldsu[aidx]             = vh;
                *(uint4*)&ldsu[CT * 1280 + aidx] = vl;
            }
            const int bidx = 2 * CT * 1280 + row * 20 + wv * 4;
            vh.x = pack_lo16(Bu[1], Bu[0]); vl.x = pack_hi16(Bu[1], Bu[0]);
            vh.y = pack_lo16(Bu[3], Bu[2]); vl.y = pack_hi16(Bu[3], Bu[2]);
            vh.z = pack_lo16(Bu[5], Bu[4]); vl.z = pack_hi16(Bu[5], Bu[4]);
            vh.w = pack_lo16(Bu[7], Bu[6]); vl.w = pack_hi16(Bu[7], Bu[6]);
            *(uint4*)&ldsu[bidx]        = vh;
            *(uint4*)&ldsu[bidx + 1280] = vl;
        }
        __syncthreads();
        if (it + 1 < KT) { gatherA(it + 1); gatherB(n0, n1); }

        const short* AsH = lds;
        const short* AsL = lds + CT * 2560;
        const short* BsH = lds + 2 * CT * 2560;
        const short* BsL = BsH + 2560;
        short8 bH[2], bL[2];
#pragma unroll
        for (int tq = 0; tq < 2; ++tq) {
            const int rb = (pw * 32 + tq * 16 + r15) * 40 + kg * 8;
            bH[tq] = *(const short8*)&BsH[rb];
            bL[tq] = *(const short8*)&BsL[rb];
        }
#pragma unroll
        for (int c2 = 0; c2 < CT; ++c2) {
            short8 aH[2], aL[2];
#pragma unroll
            for (int tq = 0; tq < 2; ++tq) {
                const int ra = (c2 * 64 + cw * 32 + tq * 16 + r15) * 40 + kg * 8;
                aH[tq] = *(const short8*)&AsH[ra];
                aL[tq] = *(const short8*)&AsL[ra];
            }
#pragma unroll
            for (int ct = 0; ct < 2; ++ct)
#pragma unroll
                for (int pt = 0; pt < 2; ++pt) {
                    acc[c2][ct][pt] = __builtin_amdgcn_mfma_f32_16x16x32_bf16(aH[ct], bH[pt], acc[c2][ct][pt], 0, 0, 0);
                    acc[c2][ct][pt] = __builtin_amdgcn_mfma_f32_16x16x32_bf16(aH[ct], bL[pt], acc[c2][ct][pt], 0, 0, 0);
                    acc[c2][ct][pt] = __builtin_amdgcn_mfma_f32_16x16x32_bf16(aL[ct], bH[pt], acc[c2][ct][pt], 0, 0, 0);
                }
        }
        __syncthreads();
    }

    // C/D: col = lane&15 -> px, row = (lane>>4)*4+reg -> co
#pragma unroll
    for (int c2 = 0; c2 < CT; ++c2)
#pragma unroll
        for (int ct = 0; ct < 2; ++ct)
#pragma unroll
            for (int pt = 0; pt < 2; ++pt)
#pragma unroll
                for (int rg = 0; rg < 4; ++rg) {
                    int co = by * COB + c2 * 64 + cw * 32 + ct * 16 + kg * 4 + rg;
                    int px = bx * 64 + pw * 32 + pt * 16 + r15;
                    int poh = px / OW, pow_ = px % OW;
                    float v = lrelu(acc[c2][ct][pt][rg] + bias[co]);
                    size_t off = ((size_t)(bz * CO + co) * OSH + (poh + OR0)) * OSW + (pow_ + OC0);
                    if (POUT) ((unsigned*)outv)[off] = pack_bf16pair(v);
                    else      ((float*)outv)[off]    = v;
                }
}

// ---------------------------------------------------------------------------
// FC as bf16 hi/lo split-GEMM on MFMA — ksplit=40 (slice 320 = 10 x BK32).
// 4x8x40 = 1280 blocks = 5/CU (was 512 = 2/CU, latency-bound like pre-R10
// conv2). Same verified tile/LDS/frag structure.
// ---------------------------------------------------------------------------
__global__ __launch_bounds__(256, 4) void fc_mfma_k(
    const unsigned* __restrict__ Sp,   // packed [1024][12800]
    const unsigned* __restrict__ Wp,   // packed [256][12800]
    float* __restrict__ part)          // [40][1024][256]
{
    // dword offsets: AH 0 | AL 2560 | BH 5120 | BL 6400 ; total 7680 dw
    __shared__ unsigned ldsu[7680];
    short* const lds = (short*)ldsu;

    const int tid  = threadIdx.x;
    const int lane = tid & 63;
    const int wv   = tid >> 6;
    const int bn = blockIdx.x, bm = blockIdx.y, ks = blockIdx.z;

    const int ra = tid & 127, ca = tid >> 7;
    const int rb = tid & 63,  cb = tid >> 6;
    const unsigned* __restrict__ aptr = Sp + (size_t)(bm * 128 + ra) * 12800 + ks * 320;
    const unsigned* __restrict__ bptr = Wp + (size_t)(bn * 64 + rb) * 12800 + ks * 320;

    unsigned Au[16], Bu[8];
    auto gather = [&](int it) {
        const int k0 = it * 32;
#pragma unroll
        for (int j = 0; j < 8; ++j) {
            Au[j]     = aptr[k0 + ca * 8 + j];
            Au[8 + j] = aptr[k0 + (ca + 2) * 8 + j];
            Bu[j]     = bptr[k0 + cb * 8 + j];
        }
    };

    f32x4 acc[2][4] = {};
    const int r15 = lane & 15, kg = lane >> 4;

    gather(0);
    for (int it = 0; it < 10; ++it) {
        {
            uint4 vh, vl;
            vh.x = pack_lo16(Au[1], Au[0]); vl.x = pack_hi16(Au[1], Au[0]);
            vh.y = pack_lo16(Au[3], Au[2]); vl.y = pack_hi16(Au[3], Au[2]);
            vh.z = pack_lo16(Au[5], Au[4]); vl.z = pack_hi16(Au[5], Au[4]);
            vh.w = pack_lo16(Au[7], Au[6]); vl.w = pack_hi16(Au[7], Au[6]);
            *(uint4*)&ldsu[ra * 20 + ca * 4]        = vh;
            *(uint4*)&ldsu[2560 + ra * 20 + ca * 4] = vl;
            vh.x = pack_lo16(Au[9],  Au[8]);  vl.x = pack_hi16(Au[9],  Au[8]);
            vh.y = pack_lo16(Au[11], Au[10]); vl.y = pack_hi16(Au[11], Au[10]);
            vh.z = pack_lo16(Au[13], Au[12]); vl.z = pack_hi16(Au[13], Au[12]);
            vh.w = pack_lo16(Au[15], Au[14]); vl.w = pack_hi16(Au[15], Au[14]);
            *(uint4*)&ldsu[ra * 20 + (ca + 2) * 4]        = vh;
            *(uint4*)&ldsu[2560 + ra * 20 + (ca + 2) * 4] = vl;
            vh.x = pack_lo16(Bu[1], Bu[0]); vl.x = pack_hi16(Bu[1], Bu[0]);
            vh.y = pack_lo16(Bu[3], Bu[2]); vl.y = pack_hi16(Bu[3], Bu[2]);
            vh.z = pack_lo16(Bu[5], Bu[4]); vl.z = pack_hi16(Bu[5], Bu[4]);
            vh.w = pack_lo16(Bu[7], Bu[6]); vl.w = pack_hi16(Bu[7], Bu[6]);
            *(uint4*)&ldsu[5120 + rb * 20 + cb * 4] = vh;
            *(uint4*)&ldsu[6400 + rb * 20 + cb * 4] = vl;
        }
        __syncthreads();
        if (it + 1 < 10) gather(it + 1);

        const short* AsH = lds;
        const short* AsL = AsH + 5120;
        const short* BsH = AsH + 10240;
        const short* BsL = AsH + 12800;
        short8 aH[2], aL[2], bH[4], bL[4];
#pragma unroll
        for (int mq = 0; mq < 2; ++mq) {
            const int rr = (wv * 32 + mq * 16 + r15) * 40 + kg * 8;
            aH[mq] = *(const short8*)&AsH[rr];
            aL[mq] = *(const short8*)&AsL[rr];
        }
#pragma unroll
        for (int nq = 0; nq < 4; ++nq) {
            const int rr = (nq * 16 + r15) * 40 + kg * 8;
            bH[nq] = *(const short8*)&BsH[rr];
            bL[nq] = *(const short8*)&BsL[rr];
        }
#pragma unroll
        for (int mq = 0; mq < 2; ++mq)
#pragma unroll
            for (int nq = 0; nq < 4; ++nq) {
                acc[mq][nq] = __builtin_amdgcn_mfma_f32_16x16x32_bf16(aH[mq], bH[nq], acc[mq][nq], 0, 0, 0);
                acc[mq][nq] = __builtin_amdgcn_mfma_f32_16x16x32_bf16(aH[mq], bL[nq], acc[mq][nq], 0, 0, 0);
                acc[mq][nq] = __builtin_amdgcn_mfma_f32_16x16x32_bf16(aL[mq], bH[nq], acc[mq][nq], 0, 0, 0);
            }
        __syncthreads();
    }

    float* __restrict__ po = part + (size_t)ks * 262144;
#pragma unroll
    for (int mq = 0; mq < 2; ++mq)
#pragma unroll
        for (int nq = 0; nq < 4; ++nq)
#pragma unroll
            for (int rg = 0; rg < 4; ++rg) {
                int m = bm * 128 + wv * 32 + mq * 16 + kg * 4 + rg;
                int ncol = bn * 64 + nq * 16 + r15;
                po[(size_t)m * 256 + ncol] = acc[mq][nq][rg];
            }
}

// ---------------------------------------------------------------------------
// ROI bilinear sampling — channel-split x4. fp32 c3 -> packed S.
// ---------------------------------------------------------------------------
__global__ __launch_bounds__(256) void roi_k(const float* __restrict__ feat,
                                             const float* __restrict__ roi,
                                             unsigned* __restrict__ S) {
    int b = blockIdx.x >> 5;
    int r = blockIdx.x & 31;
    int z = blockIdx.y;                 // channel quarter: c in [z*32, z*32+32)
    const float* rr = roi + (size_t)(b * 32 + r) * 7;

    __shared__ int   offA[100], offB[100], offC[100], offD[100];
    __shared__ float wA[100], wB[100], wC[100], wD[100];

    int tid = threadIdx.x;
    if (tid < 100) {
        int i = tid / 10, j = tid % 10;
        float cx = rr[0], cy = rr[1];
        float W1 = rr[2], W2 = rr[3], H1 = rr[4], H2 = rr[5], psi = rr[6];
        float offx = ((float)j - 4.5f) / 10.0f;
        float offy = ((float)i - 4.5f) / 10.0f;
        float gx = offx * (W1 + W2) - (W1 - W2) * 0.5f;
        float gy = offy * (H1 + H2) - (H1 - H2) * 0.5f;
        float sn = sinf(psi), cs = cosf(psi);
        float xs = gx * cs + gy * sn + cx;
        float ys = -gx * sn + gy * cs + cy;

        float x0f = floorf(xs), y0f = floorf(ys);
        int x0 = (int)x0f, x1 = x0 + 1;
        int y0 = (int)y0f, y1 = y0 + 1;
        x0 = min(max(x0, 0), 55); x1 = min(max(x1, 0), 55);
        y0 = min(max(y0, 0), 55); y1 = min(max(y1, 0), 55);
        float fx0 = (float)x0, fx1 = (float)x1;
        float fy0 = (float)y0, fy1 = (float)y1;
        float step = (fx1 - fx0) * (fy1 - fy0);
        step = fminf(fmaxf(step, 0.001f), 2.0f);
        float inv = 1.0f / step;
        wA[tid] = (fx1 - xs) * (fy1 - ys) * inv;
        wB[tid] = (fx1 - xs) * (ys - fy0) * inv;
        wC[tid] = (xs - fx0) * (fy1 - ys) * inv;
        wD[tid] = (xs - fx0) * (ys - fy0) * inv;
        offA[tid] = y0 * 56 + x0;
        offB[tid] = y1 * 56 + x0;
        offC[tid] = y0 * 56 + x1;
        offD[tid] = y1 * 56 + x1;
    }
    __syncthreads();

    const float* __restrict__ fb = feat + (size_t)b * 128 * 3136;
    unsigned* __restrict__ outb = S + ((size_t)b * 128 * 32 + r) * 100;
    for (int t = tid; t < 3200; t += 256) {
        int c = z * 32 + t / 100;
        int p = t % 100;
        const float* f = fb + c * 3136;
        float v = wA[p] * f[offA[p]] + wB[p] * f[offB[p]] +
                  wC[p] * f[offC[p]] + wD[p] * f[offD[p]];
        outb[(size_t)c * 3200 + p] = pack_bf16pair(v);
    }
}

__global__ __launch_bounds__(256) void fc2_reduce_k(const float* __restrict__ part,
                                                    const float* __restrict__ bias,
                                                    float* __restrict__ out) {
    int i = blockIdx.x * 256 + threadIdx.x;   // 0..262143
    float s = bias[i & 255];
    for (int ks = 0; ks < 40; ++ks) s += part[(size_t)ks * 262144 + i];
    out[i] = s;
}

// ---------------------------------------------------------------------------
extern "C" void kernel_launch(void* const* d_in, const int* in_sizes, int n_in,
                              void* d_out, int out_size, void* d_ws, size_t ws_size,
                              hipStream_t stream) {
    const float* x   = (const float*)d_in[0];
    const float* ROI = (const float*)d_in[1];
    const float* w1  = (const float*)d_in[2];
    const float* b1  = (const float*)d_in[3];
    const float* w2  = (const float*)d_in[4];
    const float* b2  = (const float*)d_in[5];
    const float* w3  = (const float*)d_in[6];
    const float* b3  = (const float*)d_in[7];
    const float* fcw = (const float*)d_in[8];
    const float* fcb = (const float*)d_in[9];
    float* out = (float*)d_out;

    char* ws = (char*)d_ws;
    // Workspace:
    //  c1p  [0,           57,016,320)  conv1 (packed) -> conv2
    //  c2p  [57,016,320,  87,425,024)  conv2 (packed) -> conv3
    //  xpad [87,425,024, 107,386,880)  pad (packed) -> conv1  (dead after conv1)
    //  wT1p [107,386,880, 107,399,168) packed (conv1, 96x32)
    //  wT2p [107,399,168, 107,603,968) packed (conv2)
    //  wT3p [107,603,968, 107,898,880) packed (conv3)
    //  wfcp [110,100,480, 123,207,680) packed fcw (setup; disjoint from all)
    //  c3   [0,           51,380,224)  conv3 (fp32) -> roi   (c1p dead)
    //  S    [57,016,320, 109,445,120)  roi (PACKED) -> fc    (c2p dead)
    //  part [0,           41,943,040)  fc (40 slices) -> reduce (c3 dead)
    unsigned* c1p  = (unsigned*)(ws);
    unsigned* c2p  = (unsigned*)(ws + 57016320);
    unsigned* xpad = (unsigned*)(ws + 87425024);
    unsigned* wT1p = (unsigned*)(ws + 107386880);
    unsigned* wT2p = (unsigned*)(ws + 107399168);
    unsigned* wT3p = (unsigned*)(ws + 107603968);
    unsigned* wfcp = (unsigned*)(ws + 110100480);
    float* c3   = (float*)(ws);
    unsigned* S = (unsigned*)(ws + 57016320);
    float* part = (float*)(ws);

    // Fused front-end (R17-verified): weight packs + pad + borders + fcw pack
    setup_k<<<11604, 256, 0, stream>>>(w1, wT1p, w2, wT2p, w3, wT3p,
                                       x, xpad, c1p, c2p, fcw, wfcp);

    // conv1 (MFMA): packed xpad -> packed c1p. 32co x 128px, KP=96.
    conv1_mfma_k<<<dim3(98, 32), 256, 0, stream>>>(xpad, wT1p, b1, c1p);

    // conv2 (MFMA CT=1 — R16-verified): packed c1p -> packed c2p.
    conv_mfma_k<32, 2, 5, 5, 800, 116, 120, 2, 64, 56, 58, 64, 1, 4, true, 1>
        <<<dim3(49, 1, 32), 256, 0, stream>>>(c1p, wT2p, b2, c2p);

    // conv3 (MFMA CT=2 — R16-verified): one block = all 128 co.
    conv_mfma_k<64, 1, 3, 3, 576, 58, 64, 3, 128, 56, 56, 56, 0, 0, false, 2>
        <<<dim3(49, 1, 32), 256, 0, stream>>>(c2p, wT3p, b3, c3);

    // ROI sampling: fp32 c3 -> packed S (channel-split x4)
    roi_k<<<dim3(1024, 4), 256, 0, stream>>>(c3, ROI, S);
    // FC (MFMA): ksplit=40 (5 blocks/CU) + reduce
    fc_mfma_k<<<dim3(4, 8, 40), 256, 0, stream>>>(S, wfcp, part);
    fc2_reduce_k<<<1024, 256, 0, stream>>>(part, fcb, out);
}

// Round 19
// 347.199 us; speedup vs baseline: 1.0272x; 1.0272x over previous
//
#include <hip/hip_runtime.h>
#include <hip/hip_bf16.h>

#define LEAK 0.2f

__device__ __forceinline__ float lrelu(float a) { return a > 0.0f ? a : LEAK * a; }

typedef __attribute__((ext_vector_type(8))) short short8;
typedef __attribute__((ext_vector_type(4))) float f32x4;

// bf16 RNE rounding done manually (no dependence on __hip_bfloat16 ABI).
__device__ __forceinline__ unsigned short bf16_hi_bits(float x) {
    unsigned u = __builtin_bit_cast(unsigned, x);
    unsigned r = u + 0x7fffu + ((u >> 16) & 1u);
    return (unsigned short)(r >> 16);
}
__device__ __forceinline__ float bf16_to_f32(unsigned short h) {
    unsigned u = ((unsigned)h) << 16;
    return __builtin_bit_cast(float, u);
}
__device__ __forceinline__ unsigned pack_bf16pair(float x) {
    unsigned short h = bf16_hi_bits(x);
    float lo = x - bf16_to_f32(h);
    return (unsigned)h | ((unsigned)bf16_hi_bits(lo) << 16);
}

// v_perm_b32 pair-packers: dwords are packed {hi-bf16 in low16, lo-bf16 in high16}.
__device__ __forceinline__ unsigned pack_lo16(unsigned o, unsigned e) {
    return __builtin_amdgcn_perm(o, e, 0x05040100u);
}
__device__ __forceinline__ unsigned pack_hi16(unsigned o, unsigned e) {
    return __builtin_amdgcn_perm(o, e, 0x07060302u);
}

// ---------------------------------------------------------------------------
// Fused setup (R17-verified): all independent front-end work in ONE launch.
// ---------------------------------------------------------------------------
__global__ __launch_bounds__(256) void setup_k(
    const float* __restrict__ w1, unsigned* __restrict__ wT1p,
    const float* __restrict__ w2, unsigned* __restrict__ wT2p,
    const float* __restrict__ w3, unsigned* __restrict__ wT3p,
    const float* __restrict__ x,  unsigned* __restrict__ xp,
    unsigned* __restrict__ c1p, unsigned* __restrict__ c2p,
    const float* __restrict__ fcw, unsigned* __restrict__ wfcp)
{
    const int blk = blockIdx.x;
    const int tid = threadIdx.x;

    if (blk < 12) {                       // wtr1: 96x32
        int i = blk * 256 + tid;
        if (i < 96 * 32) {
            int k = i / 32, co = i % 32;
            float v = (k < 75) ? w1[(size_t)co * 75 + k] : 0.0f;
            wT1p[i] = pack_bf16pair(v);
        }
    } else if (blk < 212) {               // wtr2: 800x64
        int i = (blk - 12) * 256 + tid;
        if (i < 800 * 64) {
            int k = i / 64, co = i % 64;
            wT2p[i] = pack_bf16pair(w2[(size_t)co * 800 + k]);
        }
    } else if (blk < 500) {               // wtr3: 576x128
        int i = (blk - 212) * 256 + tid;
        if (i < 576 * 128) {
            int k = i / 128, co = i % 128;
            wT3p[i] = pack_bf16pair(w3[(size_t)co * 576 + k]);
        }
    } else if (blk < 5972) {              // pad_x: 32*3*57 blocks
        int b2 = blk - 500;
        int r4 = b2 % 57, ic = b2 / 57;
        int wid = tid >> 6, lane = tid & 63;
        int row = r4 * 4 + wid;
        const float* __restrict__ src = x + (size_t)ic * 224 * 224 + (size_t)(row - 2) * 224;
        unsigned* __restrict__ dst = xp + (size_t)ic * 228 * 228 + (size_t)row * 228;
        bool rok = (row >= 2) && (row < 226);
        for (int c = lane; c < 228; c += 64) {
            float v = 0.0f;
            if (rok && c >= 2 && c < 226) v = src[c - 2];
            dst[c] = pack_bf16pair(v);
        }
    } else if (blk < 6996) {              // zb c1p: 1024 planes
        unsigned* base = c1p + (size_t)(blk - 5972) * (116 * 120);
        for (int t = tid; t < 928; t += 256) {
            int idx;
            if (t < 480) {
                int r = t / 120, c = t - r * 120;
                int row = (r < 2) ? r : r + 112;
                idx = row * 120 + c;
            } else {
                int s = t - 480;
                int r = s >> 2, c = s & 3;
                int col = (c < 2) ? (c + 2) : (c + 114);
                idx = (r + 2) * 120 + col;
            }
            base[idx] = 0u;
        }
    } else if (blk < 7508) {              // zb c2p: 2048 planes, 4 per block
        int plane = (blk - 6996) * 4 + (tid >> 6);
        int lane  = tid & 63;
        unsigned* base = c2p + (size_t)plane * (58 * 64);
        for (int t = lane; t < 240; t += 64) {
            int idx;
            if (t < 128) {
                int r = t >> 6, c = t & 63;
                idx = (r ? 57 : 0) * 64 + c;
            } else {
                int s = t - 128;
                int r = (s >> 1) + 1;
                idx = r * 64 + ((s & 1) ? 60 : 3);
            }
            base[idx] = 0u;
        }
    } else {                              // split_pack fcw: 3,276,800 elems
        for (int i = (blk - 7508) * 256 + tid; i < 3276800; i += 4096 * 256)
            wfcp[i] = pack_bf16pair(fcw[i]);
    }
}

// ---------------------------------------------------------------------------
// conv1 as bf16 hi/lo split-GEMM on MFMA (R11-verified). CO=32, KP=96, ST=2.
// ---------------------------------------------------------------------------
__global__ __launch_bounds__(256, 4) void conv1_mfma_k(
    const unsigned* __restrict__ src,   // packed xpad [img*3+ci][228][228]
    const unsigned* __restrict__ wp,    // packed wT1 [96][32]
    const float* __restrict__ bias,
    unsigned* __restrict__ outp)        // packed c1p [img*32+co][116][120]
{
    // dwords: AH 0(640) | AL 640 | BH 1280(2560) | BL 3840 ; total 6400 dw
    __shared__ unsigned ldsu[6400];
    __shared__ int offtab[96];
    short* const lds = (short*)ldsu;

    const int tid  = threadIdx.x;
    const int lane = tid & 63;
    const int wv   = tid >> 6;
    const int bx   = blockIdx.x;        // 98 px tiles
    const int bz   = blockIdx.y;        // 32 imgs

    if (tid < 96) {
        int k = min(tid, 74);           // clamp padded-K tail
        int ci = k / 25, r = k - ci * 25;
        int kh = r / 5, kw = r - kh * 5;
        offtab[tid] = (ci * 228 + kh) * 228 + kw;
    }
    __syncthreads();

    const int brow = tid & 127, half = tid >> 7;
    const int bn   = bx * 128 + brow;
    const int boh  = bn / 112, bow = bn % 112;
    const unsigned* __restrict__ bsrc =
        src + ((size_t)(bz * 3) * 228 + boh * 2) * 228 + bow * 2;
    const int arow = tid & 31, ks = (tid >> 5) & 3;

    unsigned Bu[16], Au[8];
    auto gather = [&](int it) {
        const int k0 = it * 32;
#pragma unroll
        for (int c = 0; c < 2; ++c) {
            int kb = k0 + (half * 2 + c) * 8;
            int4 o0 = *(const int4*)&offtab[kb];
            int4 o1 = *(const int4*)&offtab[kb + 4];
            Bu[c * 8 + 0] = bsrc[o0.x]; Bu[c * 8 + 1] = bsrc[o0.y];
            Bu[c * 8 + 2] = bsrc[o0.z]; Bu[c * 8 + 3] = bsrc[o0.w];
            Bu[c * 8 + 4] = bsrc[o1.x]; Bu[c * 8 + 5] = bsrc[o1.y];
            Bu[c * 8 + 6] = bsrc[o1.z]; Bu[c * 8 + 7] = bsrc[o1.w];
        }
        if (tid < 128) {
            const unsigned* __restrict__ wk = wp + (size_t)(k0 + ks * 8) * 32 + arow;
#pragma unroll
            for (int j = 0; j < 8; ++j) Au[j] = wk[j * 32];
        }
    };

    f32x4 acc[2][2] = {};
    const int r15 = lane & 15, kg = lane >> 4;

    gather(0);
    for (int it = 0; it < 3; ++it) {
        {
            uint4 vh, vl;
#pragma unroll
            for (int c = 0; c < 2; ++c) {
                vh.x = pack_lo16(Bu[c*8+1], Bu[c*8+0]); vl.x = pack_hi16(Bu[c*8+1], Bu[c*8+0]);
                vh.y = pack_lo16(Bu[c*8+3], Bu[c*8+2]); vl.y = pack_hi16(Bu[c*8+3], Bu[c*8+2]);
                vh.z = pack_lo16(Bu[c*8+5], Bu[c*8+4]); vl.z = pack_hi16(Bu[c*8+5], Bu[c*8+4]);
                vh.w = pack_lo16(Bu[c*8+7], Bu[c*8+6]); vl.w = pack_hi16(Bu[c*8+7], Bu[c*8+6]);
                *(uint4*)&ldsu[1280 + brow * 20 + (half * 2 + c) * 4] = vh;
                *(uint4*)&ldsu[3840 + brow * 20 + (half * 2 + c) * 4] = vl;
            }
            if (tid < 128) {
                vh.x = pack_lo16(Au[1], Au[0]); vl.x = pack_hi16(Au[1], Au[0]);
                vh.y = pack_lo16(Au[3], Au[2]); vl.y = pack_hi16(Au[3], Au[2]);
                vh.z = pack_lo16(Au[5], Au[4]); vl.z = pack_hi16(Au[5], Au[4]);
                vh.w = pack_lo16(Au[7], Au[6]); vl.w = pack_hi16(Au[7], Au[6]);
                *(uint4*)&ldsu[arow * 20 + ks * 4]       = vh;
                *(uint4*)&ldsu[640 + arow * 20 + ks * 4] = vl;
            }
        }
        __syncthreads();
        if (it + 1 < 3) gather(it + 1);

        const short* AsH = lds;
        const short* AsL = lds + 1280;
        const short* BsH = lds + 2560;
        const short* BsL = lds + 7680;
        short8 aH[2], aL[2], bH[2], bL[2];
#pragma unroll
        for (int tq = 0; tq < 2; ++tq) {
            const int ra = (tq * 16 + r15) * 40 + kg * 8;
            aH[tq] = *(const short8*)&AsH[ra];
            aL[tq] = *(const short8*)&AsL[ra];
            const int rb = (wv * 32 + tq * 16 + r15) * 40 + kg * 8;
            bH[tq] = *(const short8*)&BsH[rb];
            bL[tq] = *(const short8*)&BsL[rb];
        }
#pragma unroll
        for (int ct = 0; ct < 2; ++ct)
#pragma unroll
            for (int pt = 0; pt < 2; ++pt) {
                acc[ct][pt] = __builtin_amdgcn_mfma_f32_16x16x32_bf16(aH[ct], bH[pt], acc[ct][pt], 0, 0, 0);
                acc[ct][pt] = __builtin_amdgcn_mfma_f32_16x16x32_bf16(aH[ct], bL[pt], acc[ct][pt], 0, 0, 0);
                acc[ct][pt] = __builtin_amdgcn_mfma_f32_16x16x32_bf16(aL[ct], bH[pt], acc[ct][pt], 0, 0, 0);
            }
        __syncthreads();
    }

    // C/D: col = lane&15 -> px, row = (lane>>4)*4+reg -> co
#pragma unroll
    for (int ct = 0; ct < 2; ++ct)
#pragma unroll
        for (int pt = 0; pt < 2; ++pt)
#pragma unroll
            for (int rg = 0; rg < 4; ++rg) {
                int co = ct * 16 + kg * 4 + rg;
                int px = bx * 128 + wv * 32 + pt * 16 + r15;
                int poh = px / 112, pw_ = px % 112;
                float v = acc[ct][pt][rg] + bias[co];
                outp[((size_t)(bz * 32 + co) * 116 + poh + 2) * 120 + pw_ + 4] =
                    pack_bf16pair(lrelu(v));
            }
}

// ---------------------------------------------------------------------------
// Conv as bf16 hi/lo split-GEMM on MFMA (conv2/conv3) — v3 + co-tiling CT
// (R16-verified: conv2 CT=1 ~73us, conv3 CT=2).
// ---------------------------------------------------------------------------
template<int CI, int ST, int KH, int KW, int KP,
         int PIH, int PIW, int LP,
         int CO, int OW, int OSH, int OSW, int OR0, int OC0, bool POUT, int CT>
__global__ __launch_bounds__(256, 4) void conv_mfma_k(
    const unsigned* __restrict__ src,   // packed act [img*CI+ci][PIH][PIW]
    const unsigned* __restrict__ wp,    // packed wT  [KP][CO]
    const float* __restrict__ bias,
    void* __restrict__ outv)
{
    constexpr int KT  = KP / 32;
    constexpr int COB = CT * 64;        // co per block
    __shared__ unsigned ldsu[CT * 2560 + 2560];
    __shared__ int offtab[KP];
    short* const lds = (short*)ldsu;

    const int tid  = threadIdx.x;
    const int lane = tid & 63;
    const int wv   = tid >> 6;          // wave 0..3
    const int bx   = blockIdx.x;        // 49 px tiles
    const int by   = blockIdx.y;        // CO/COB co tiles
    const int bz   = blockIdx.z;        // 32 imgs

    for (int k = tid; k < KP; k += 256) {
        int ci = k / (KH * KW), r = k - ci * (KH * KW);
        int kh = r / KW, kw = r - kh * KW;
        offtab[k] = (ci * PIH + kh) * PIW + kw;
    }
    __syncthreads();

    const int row = lane;               // staging row; k-slot = wave (8 k each)
    const int n   = bx * 64 + row;      // 0..3135
    const int oh  = n / OW, ow = n % OW;
    const unsigned* __restrict__ bsrc =
        src + ((size_t)(bz * CI) * PIH + oh * ST) * PIW + ow * ST + LP;
    const unsigned* __restrict__ wsrc = wp + (size_t)(wv * 8) * CO + by * COB + row;

    unsigned Au[CT][8], Bu[8];
    auto gatherA = [&](int it) {
        const unsigned* __restrict__ wk = wsrc + (size_t)it * 32 * CO;
#pragma unroll
        for (int c2 = 0; c2 < CT; ++c2)
#pragma unroll
            for (int j = 0; j < 8; ++j) Au[c2][j] = wk[j * CO + c2 * 64];
    };
    auto gatherB = [&](int4 o0, int4 o1) {
        Bu[0] = bsrc[o0.x]; Bu[1] = bsrc[o0.y]; Bu[2] = bsrc[o0.z]; Bu[3] = bsrc[o0.w];
        Bu[4] = bsrc[o1.x]; Bu[5] = bsrc[o1.y]; Bu[6] = bsrc[o1.z]; Bu[7] = bsrc[o1.w];
    };

    f32x4 acc[CT][2][2] = {};

    const int cw = wv & 1, pw = wv >> 1;
    const int r15 = lane & 15, kg = lane >> 4;

    int4 o0 = *(const int4*)&offtab[wv * 8];
    int4 o1 = *(const int4*)&offtab[wv * 8 + 4];
    gatherA(0); gatherB(o0, o1);
    for (int it = 0; it < KT; ++it) {
        int4 n0, n1;
        if (it + 1 < KT) {
            const int nk = (it + 1) * 32 + wv * 8;
            n0 = *(const int4*)&offtab[nk];
            n1 = *(const int4*)&offtab[nk + 4];
        }
        {
            uint4 vh, vl;
#pragma unroll
            for (int c2 = 0; c2 < CT; ++c2) {
                const int aidx = (c2 * 64 + row) * 20 + wv * 4;
                vh.x = pack_lo16(Au[c2][1], Au[c2][0]); vl.x = pack_hi16(Au[c2][1], Au[c2][0]);
                vh.y = pack_lo16(Au[c2][3], Au[c2][2]); vl.y = pack_hi16(Au[c2][3], Au[c2][2]);
                vh.z = pack_lo16(Au[c2][5], Au[c2][4]); vl.z = pack_hi16(Au[c2][5], Au[c2][4]);
                vh.w = pack_lo16(Au[c2][7], Au[c2][6]); vl.w = pack_hi16(Au[c2][7], Au[c2][6]);
                *(uint4*)&ldsu[aidx]             = vh;
                *(uint4*)&ldsu[CT * 1280 + aidx] = vl;
            }
            const int bidx = 2 * CT * 1280 + row * 20 + wv * 4;
            vh.x = pack_lo16(Bu[1], Bu[0]); vl.x = pack_hi16(Bu[1], Bu[0]);
            vh.y = pack_lo16(Bu[3], Bu[2]); vl.y = pack_hi16(Bu[3], Bu[2]);
            vh.z = pack_lo16(Bu[5], Bu[4]); vl.z = pack_hi16(Bu[5], Bu[4]);
            vh.w = pack_lo16(Bu[7], Bu[6]); vl.w = pack_hi16(Bu[7], Bu[6]);
            *(uint4*)&ldsu[bidx]        = vh;
            *(uint4*)&ldsu[bidx + 1280] = vl;
        }
        __syncthreads();
        if (it + 1 < KT) { gatherA(it + 1); gatherB(n0, n1); }

        const short* AsH = lds;
        const short* AsL = lds + CT * 2560;
        const short* BsH = lds + 2 * CT * 2560;
        const short* BsL = BsH + 2560;
        short8 bH[2], bL[2];
#pragma unroll
        for (int tq = 0; tq < 2; ++tq) {
            const int rb = (pw * 32 + tq * 16 + r15) * 40 + kg * 8;
            bH[tq] = *(const short8*)&BsH[rb];
            bL[tq] = *(const short8*)&BsL[rb];
        }
#pragma unroll
        for (int c2 = 0; c2 < CT; ++c2) {
            short8 aH[2], aL[2];
#pragma unroll
            for (int tq = 0; tq < 2; ++tq) {
                const int ra = (c2 * 64 + cw * 32 + tq * 16 + r15) * 40 + kg * 8;
                aH[tq] = *(const short8*)&AsH[ra];
                aL[tq] = *(const short8*)&AsL[ra];
            }
#pragma unroll
            for (int ct = 0; ct < 2; ++ct)
#pragma unroll
                for (int pt = 0; pt < 2; ++pt) {
                    acc[c2][ct][pt] = __builtin_amdgcn_mfma_f32_16x16x32_bf16(aH[ct], bH[pt], acc[c2][ct][pt], 0, 0, 0);
                    acc[c2][ct][pt] = __builtin_amdgcn_mfma_f32_16x16x32_bf16(aH[ct], bL[pt], acc[c2][ct][pt], 0, 0, 0);
                    acc[c2][ct][pt] = __builtin_amdgcn_mfma_f32_16x16x32_bf16(aL[ct], bH[pt], acc[c2][ct][pt], 0, 0, 0);
                }
        }
        __syncthreads();
    }

    // C/D: col = lane&15 -> px, row = (lane>>4)*4+reg -> co
#pragma unroll
    for (int c2 = 0; c2 < CT; ++c2)
#pragma unroll
        for (int ct = 0; ct < 2; ++ct)
#pragma unroll
            for (int pt = 0; pt < 2; ++pt)
#pragma unroll
                for (int rg = 0; rg < 4; ++rg) {
                    int co = by * COB + c2 * 64 + cw * 32 + ct * 16 + kg * 4 + rg;
                    int px = bx * 64 + pw * 32 + pt * 16 + r15;
                    int poh = px / OW, pow_ = px % OW;
                    float v = lrelu(acc[c2][ct][pt][rg] + bias[co]);
                    size_t off = ((size_t)(bz * CO + co) * OSH + (poh + OR0)) * OSW + (pow_ + OC0);
                    if (POUT) ((unsigned*)outv)[off] = pack_bf16pair(v);
                    else      ((float*)outv)[off]    = v;
                }
}

// ---------------------------------------------------------------------------
// FC as bf16 hi/lo split-GEMM on MFMA — ksplit=16 (R17-verified best).
// ---------------------------------------------------------------------------
__global__ __launch_bounds__(256, 4) void fc_mfma_k(
    const unsigned* __restrict__ Sp,   // packed [1024][12800]
    const unsigned* __restrict__ Wp,   // packed [256][12800]
    float* __restrict__ part)          // [16][1024][256]
{
    // dword offsets: AH 0 | AL 2560 | BH 5120 | BL 6400 ; total 7680 dw
    __shared__ unsigned ldsu[7680];
    short* const lds = (short*)ldsu;

    const int tid  = threadIdx.x;
    const int lane = tid & 63;
    const int wv   = tid >> 6;
    const int bn = blockIdx.x, bm = blockIdx.y, ks = blockIdx.z;

    const int ra = tid & 127, ca = tid >> 7;
    const int rb = tid & 63,  cb = tid >> 6;
    const unsigned* __restrict__ aptr = Sp + (size_t)(bm * 128 + ra) * 12800 + ks * 800;
    const unsigned* __restrict__ bptr = Wp + (size_t)(bn * 64 + rb) * 12800 + ks * 800;

    unsigned Au[16], Bu[8];
    auto gather = [&](int it) {
        const int k0 = it * 32;
#pragma unroll
        for (int j = 0; j < 8; ++j) {
            Au[j]     = aptr[k0 + ca * 8 + j];
            Au[8 + j] = aptr[k0 + (ca + 2) * 8 + j];
            Bu[j]     = bptr[k0 + cb * 8 + j];
        }
    };

    f32x4 acc[2][4] = {};
    const int r15 = lane & 15, kg = lane >> 4;

    gather(0);
    for (int it = 0; it < 25; ++it) {
        {
            uint4 vh, vl;
            vh.x = pack_lo16(Au[1], Au[0]); vl.x = pack_hi16(Au[1], Au[0]);
            vh.y = pack_lo16(Au[3], Au[2]); vl.y = pack_hi16(Au[3], Au[2]);
            vh.z = pack_lo16(Au[5], Au[4]); vl.z = pack_hi16(Au[5], Au[4]);
            vh.w = pack_lo16(Au[7], Au[6]); vl.w = pack_hi16(Au[7], Au[6]);
            *(uint4*)&ldsu[ra * 20 + ca * 4]        = vh;
            *(uint4*)&ldsu[2560 + ra * 20 + ca * 4] = vl;
            vh.x = pack_lo16(Au[9],  Au[8]);  vl.x = pack_hi16(Au[9],  Au[8]);
            vh.y = pack_lo16(Au[11], Au[10]); vl.y = pack_hi16(Au[11], Au[10]);
            vh.z = pack_lo16(Au[13], Au[12]); vl.z = pack_hi16(Au[13], Au[12]);
            vh.w = pack_lo16(Au[15], Au[14]); vl.w = pack_hi16(Au[15], Au[14]);
            *(uint4*)&ldsu[ra * 20 + (ca + 2) * 4]        = vh;
            *(uint4*)&ldsu[2560 + ra * 20 + (ca + 2) * 4] = vl;
            vh.x = pack_lo16(Bu[1], Bu[0]); vl.x = pack_hi16(Bu[1], Bu[0]);
            vh.y = pack_lo16(Bu[3], Bu[2]); vl.y = pack_hi16(Bu[3], Bu[2]);
            vh.z = pack_lo16(Bu[5], Bu[4]); vl.z = pack_hi16(Bu[5], Bu[4]);
            vh.w = pack_lo16(Bu[7], Bu[6]); vl.w = pack_hi16(Bu[7], Bu[6]);
            *(uint4*)&ldsu[5120 + rb * 20 + cb * 4] = vh;
            *(uint4*)&ldsu[6400 + rb * 20 + cb * 4] = vl;
        }
        __syncthreads();
        if (it + 1 < 25) gather(it + 1);

        const short* AsH = lds;
        const short* AsL = AsH + 5120;
        const short* BsH = AsH + 10240;
        const short* BsL = AsH + 12800;
        short8 aH[2], aL[2], bH[4], bL[4];
#pragma unroll
        for (int mq = 0; mq < 2; ++mq) {
            const int rr = (wv * 32 + mq * 16 + r15) * 40 + kg * 8;
            aH[mq] = *(const short8*)&AsH[rr];
            aL[mq] = *(const short8*)&AsL[rr];
        }
#pragma unroll
        for (int nq = 0; nq < 4; ++nq) {
            const int rr = (nq * 16 + r15) * 40 + kg * 8;
            bH[nq] = *(const short8*)&BsH[rr];
            bL[nq] = *(const short8*)&BsL[rr];
        }
#pragma unroll
        for (int mq = 0; mq < 2; ++mq)
#pragma unroll
            for (int nq = 0; nq < 4; ++nq) {
                acc[mq][nq] = __builtin_amdgcn_mfma_f32_16x16x32_bf16(aH[mq], bH[nq], acc[mq][nq], 0, 0, 0);
                acc[mq][nq] = __builtin_amdgcn_mfma_f32_16x16x32_bf16(aH[mq], bL[nq], acc[mq][nq], 0, 0, 0);
                acc[mq][nq] = __builtin_amdgcn_mfma_f32_16x16x32_bf16(aL[mq], bH[nq], acc[mq][nq], 0, 0, 0);
            }
        __syncthreads();
    }

    float* __restrict__ po = part + (size_t)ks * 262144;
#pragma unroll
    for (int mq = 0; mq < 2; ++mq)
#pragma unroll
        for (int nq = 0; nq < 4; ++nq)
#pragma unroll
            for (int rg = 0; rg < 4; ++rg) {
                int m = bm * 128 + wv * 32 + mq * 16 + kg * 4 + rg;
                int ncol = bn * 64 + nq * 16 + r15;
                po[(size_t)m * 256 + ncol] = acc[mq][nq][rg];
            }
}

// ---------------------------------------------------------------------------
// ROI bilinear sampling — channel-split x2 (R16/R17-verified). fp32 c3 -> packed S.
// ---------------------------------------------------------------------------
__global__ __launch_bounds__(256) void roi_k(const float* __restrict__ feat,
                                             const float* __restrict__ roi,
                                             unsigned* __restrict__ S) {
    int b = blockIdx.x >> 5;
    int r = blockIdx.x & 31;
    int z = blockIdx.y;                 // channel half: c in [z*64, z*64+64)
    const float* rr = roi + (size_t)(b * 32 + r) * 7;

    __shared__ int   offA[100], offB[100], offC[100], offD[100];
    __shared__ float wA[100], wB[100], wC[100], wD[100];

    int tid = threadIdx.x;
    if (tid < 100) {
        int i = tid / 10, j = tid % 10;
        float cx = rr[0], cy = rr[1];
        float W1 = rr[2], W2 = rr[3], H1 = rr[4], H2 = rr[5], psi = rr[6];
        float offx = ((float)j - 4.5f) / 10.0f;
        float offy = ((float)i - 4.5f) / 10.0f;
        float gx = offx * (W1 + W2) - (W1 - W2) * 0.5f;
        float gy = offy * (H1 + H2) - (H1 - H2) * 0.5f;
        float sn = sinf(psi), cs = cosf(psi);
        float xs = gx * cs + gy * sn + cx;
        float ys = -gx * sn + gy * cs + cy;

        float x0f = floorf(xs), y0f = floorf(ys);
        int x0 = (int)x0f, x1 = x0 + 1;
        int y0 = (int)y0f, y1 = y0 + 1;
        x0 = min(max(x0, 0), 55); x1 = min(max(x1, 0), 55);
        y0 = min(max(y0, 0), 55); y1 = min(max(y1, 0), 55);
        float fx0 = (float)x0, fx1 = (float)x1;
        float fy0 = (float)y0, fy1 = (float)y1;
        float step = (fx1 - fx0) * (fy1 - fy0);
        step = fminf(fmaxf(step, 0.001f), 2.0f);
        float inv = 1.0f / step;
        wA[tid] = (fx1 - xs) * (fy1 - ys) * inv;
        wB[tid] = (fx1 - xs) * (ys - fy0) * inv;
        wC[tid] = (xs - fx0) * (fy1 - ys) * inv;
        wD[tid] = (xs - fx0) * (ys - fy0) * inv;
        offA[tid] = y0 * 56 + x0;
        offB[tid] = y1 * 56 + x0;
        offC[tid] = y0 * 56 + x1;
        offD[tid] = y1 * 56 + x1;
    }
    __syncthreads();

    const float* __restrict__ fb = feat + (size_t)b * 128 * 3136;
    unsigned* __restrict__ outb = S + ((size_t)b * 128 * 32 + r) * 100;
    for (int t = tid; t < 6400; t += 256) {
        int c = z * 64 + t / 100;
        int p = t % 100;
        const float* f = fb + c * 3136;
        float v = wA[p] * f[offA[p]] + wB[p] * f[offB[p]] +
                  wC[p] * f[offC[p]] + wD[p] * f[offD[p]];
        outb[(size_t)c * 3200 + p] = pack_bf16pair(v);
    }
}

__global__ __launch_bounds__(256) void fc2_reduce_k(const float* __restrict__ part,
                                                    const float* __restrict__ bias,
                                                    float* __restrict__ out) {
    int i = blockIdx.x * 256 + threadIdx.x;   // 0..262143
    float s = bias[i & 255];
    for (int ks = 0; ks < 16; ++ks) s += part[(size_t)ks * 262144 + i];
    out[i] = s;
}

// ---------------------------------------------------------------------------
extern "C" void kernel_launch(void* const* d_in, const int* in_sizes, int n_in,
                              void* d_out, int out_size, void* d_ws, size_t ws_size,
                              hipStream_t stream) {
    const float* x   = (const float*)d_in[0];
    const float* ROI = (const float*)d_in[1];
    const float* w1  = (const float*)d_in[2];
    const float* b1  = (const float*)d_in[3];
    const float* w2  = (const float*)d_in[4];
    const float* b2  = (const float*)d_in[5];
    const float* w3  = (const float*)d_in[6];
    const float* b3  = (const float*)d_in[7];
    const float* fcw = (const float*)d_in[8];
    const float* fcb = (const float*)d_in[9];
    float* out = (float*)d_out;

    char* ws = (char*)d_ws;
    // Workspace (R17-verified):
    //  c1p  [0,           57,016,320)  conv1 (packed) -> conv2
    //  c2p  [57,016,320,  87,425,024)  conv2 (packed) -> conv3
    //  xpad [87,425,024, 107,386,880)  pad (packed) -> conv1  (dead after conv1)
    //  wT1p [107,386,880, 107,399,168) packed (conv1, 96x32)
    //  wT2p [107,399,168, 107,603,968) packed (conv2)
    //  wT3p [107,603,968, 107,898,880) packed (conv3)
    //  wfcp [110,100,480, 123,207,680) packed fcw (setup; disjoint from all)
    //  c3   [0,           51,380,224)  conv3 (fp32) -> roi   (c1p dead)
    //  S    [57,016,320, 109,445,120)  roi (PACKED) -> fc    (c2p dead)
    //  part [16,777,216,  33,554,432)  fc -> reduce          (inside dead c3)
    unsigned* c1p  = (unsigned*)(ws);
    unsigned* c2p  = (unsigned*)(ws + 57016320);
    unsigned* xpad = (unsigned*)(ws + 87425024);
    unsigned* wT1p = (unsigned*)(ws + 107386880);
    unsigned* wT2p = (unsigned*)(ws + 107399168);
    unsigned* wT3p = (unsigned*)(ws + 107603968);
    unsigned* wfcp = (unsigned*)(ws + 110100480);
    float* c3   = (float*)(ws);
    unsigned* S = (unsigned*)(ws + 57016320);
    float* part = (float*)(ws + 16777216);

    // Fused front-end (R17-verified): weight packs + pad + borders + fcw pack
    setup_k<<<11604, 256, 0, stream>>>(w1, wT1p, w2, wT2p, w3, wT3p,
                                       x, xpad, c1p, c2p, fcw, wfcp);

    // conv1 (MFMA): packed xpad -> packed c1p. 32co x 128px, KP=96.
    conv1_mfma_k<<<dim3(98, 32), 256, 0, stream>>>(xpad, wT1p, b1, c1p);

    // conv2 (MFMA CT=1 — R16-verified): packed c1p -> packed c2p.
    conv_mfma_k<32, 2, 5, 5, 800, 116, 120, 2, 64, 56, 58, 64, 1, 4, true, 1>
        <<<dim3(49, 1, 32), 256, 0, stream>>>(c1p, wT2p, b2, c2p);

    // conv3 (MFMA CT=2 — R16-verified): one block = all 128 co.
    conv_mfma_k<64, 1, 3, 3, 576, 58, 64, 3, 128, 56, 56, 56, 0, 0, false, 2>
        <<<dim3(49, 1, 32), 256, 0, stream>>>(c2p, wT3p, b3, c3);

    // ROI sampling: fp32 c3 -> packed S (channel-split x2)
    roi_k<<<dim3(1024, 2), 256, 0, stream>>>(c3, ROI, S);
    // FC (MFMA): split-K 16 + reduce
    fc_mfma_k<<<dim3(4, 8, 16), 256, 0, stream>>>(S, wfcp, part);
    fc2_reduce_k<<<1024, 256, 0, stream>>>(part, fcb, out);
}